// Round 10
// baseline (116.182 us; speedup 1.0000x reference)
//
#include <hip/hip_runtime.h>
#include <hip/hip_bf16.h>

// Problem constants (B,C,T,H,W = 2,64,8,48,48)
#define CC 64
#define TT 8
#define PP 2304        // 48*48
#define C2 32
#define BT 16          // B*T
#define NKT 36         // key tiles of 64
// log2(e)/sqrt(32): folds softmax scale AND exp->exp2 into theta pre-scale
#define SCALE2 0.25503486f

using h8 = __attribute__((ext_vector_type(8))) _Float16;  // 4 VGPRs
using h4 = __attribute__((ext_vector_type(4))) _Float16;  // 2 VGPRs
using f4 = __attribute__((ext_vector_type(4))) float;     // MFMA C/D frag

#if __has_builtin(__builtin_amdgcn_exp2f)
#define EXP2(v) __builtin_amdgcn_exp2f(v)
#else
#define EXP2(v) exp2f(v)
#endif

// XCD swizzle: dispatch round-robins XCDs by linear block id; fixing
// blockIdx.x per bt puts all consumers of one bt on ONE XCD whose 4 MB L2
// holds that bt's ~870 KB record set. k_prep uses the same map so records
// are produced on the consuming XCD. Perf heuristic only.
#define SWIZ_BT(xcd, g) ((xcd) + 8 * ((g) & 1))

// Workspace (_Float16):
//  thf[bt][g16 (144 of 16p)][lane][8]   theta B-frags (pre-scaled)  2.25 MB
//  rec[bt][kt] = 12 KB record:                                      7.08 MB
//     halves [0,2048):  phi A-frags   [nt(4)][lane][8]
//     halves [2048,6144): x PV A-frags [g(2)][ct(4)][lane][8], packed in the
//       K=32 key-permuted order: slot k=quad*8+j holds key
//       32g + (j<4 ? quad*4+j : 16+quad*4+(j-4)).  With this order the PV
//       B-operand is just the concat of two S D-frag h4's -> full-rate
//       16x16x32 PV MFMAs with zero cross-lane traffic.
// Every k_attn load is base + lane*16B: fully coalesced dwordx4.

// ---------------------------------------------------------------------------
// k_prep: grid (8, 72), 512 thr = 8 waves. Waves 0-3: projections + thf +
// phi record chunks. Waves 4-7: x-chunk packing in parallel. (R9 version,
// unchanged -- measured -2.2 us vs the 256-thr serial version.)
// ---------------------------------------------------------------------------
__global__ __launch_bounds__(512) void k_prep(
    const float* __restrict__ x, const float* __restrict__ tw,
    const float* __restrict__ pw, _Float16* __restrict__ thf,
    _Float16* __restrict__ rec) {
  const int qt = blockIdx.y >> 1, bt = SWIZ_BT(blockIdx.x, blockIdx.y);
  const int b = bt >> 3, t = bt & 7;
  const int tid = threadIdx.x;
  const int wv = tid >> 6, lane = tid & 63;
  const int quad = lane >> 4, l15 = lane & 15;

  __shared__ __align__(16) float x_s[64][68];         // [q_loc][c]
  __shared__ __align__(16) _Float16 th_s[4][16][32];  // per-wave [q16][c2]
  __shared__ __align__(16) _Float16 ph_s[4][16][32];

  const size_t xslice = ((size_t)b * CC * TT + t) * PP;
  const int qg0 = qt * 64;
  _Float16* rb = rec + (size_t)(bt * NKT + qt) * 6144;
  const f4 zero = {0.f, 0.f, 0.f, 0.f};

  // stage x patch (64c x 64q) transposed to [q][c]; 512 thr, 2 passes
  {
    const int l16 = tid & 15;
    const int crow = tid >> 4;  // 0..31
#pragma unroll
    for (int ppass = 0; ppass < 2; ppass++) {
      const int c = ppass * 32 + crow;
      float4 u = *reinterpret_cast<const float4*>(
          &x[xslice + (size_t)c * (TT * PP) + qg0 + l16 * 4]);
      x_s[l16 * 4 + 0][c] = u.x;
      x_s[l16 * 4 + 1][c] = u.y;
      x_s[l16 * 4 + 2][c] = u.z;
      x_s[l16 * 4 + 3][c] = u.w;
    }
  }
  __syncthreads();

  if (wv < 4) {
    // projections: D[m=c2][n=q_loc] = W[c2][c] . x[q_loc][c], K=64
    h8 bx[2];
#pragma unroll
    for (int ks = 0; ks < 2; ks++) {
      const float* row = &x_s[wv * 16 + l15][ks * 32 + quad * 8];
      float4 u0 = *reinterpret_cast<const float4*>(row);
      float4 u1 = *reinterpret_cast<const float4*>(row + 4);
      bx[ks][0] = (_Float16)u0.x; bx[ks][1] = (_Float16)u0.y;
      bx[ks][2] = (_Float16)u0.z; bx[ks][3] = (_Float16)u0.w;
      bx[ks][4] = (_Float16)u1.x; bx[ks][5] = (_Float16)u1.y;
      bx[ks][6] = (_Float16)u1.z; bx[ks][7] = (_Float16)u1.w;
    }

    const float* twt = tw + t * C2 * CC;
    const float* pwt = pw + t * C2 * CC;
    f4 accT[2] = {zero, zero}, accP[2] = {zero, zero};
#pragma unroll
    for (int mt = 0; mt < 2; mt++)
#pragma unroll
      for (int ks = 0; ks < 2; ks++) {
        const float* wr = twt + (mt * 16 + l15) * CC + ks * 32 + quad * 8;
        const float* pr = pwt + (mt * 16 + l15) * CC + ks * 32 + quad * 8;
        float4 a0 = *reinterpret_cast<const float4*>(wr);
        float4 a1 = *reinterpret_cast<const float4*>(wr + 4);
        float4 p0 = *reinterpret_cast<const float4*>(pr);
        float4 p1 = *reinterpret_cast<const float4*>(pr + 4);
        h8 at = {(_Float16)a0.x, (_Float16)a0.y, (_Float16)a0.z,
                 (_Float16)a0.w, (_Float16)a1.x, (_Float16)a1.y,
                 (_Float16)a1.z, (_Float16)a1.w};
        h8 ap = {(_Float16)p0.x, (_Float16)p0.y, (_Float16)p0.z,
                 (_Float16)p0.w, (_Float16)p1.x, (_Float16)p1.y,
                 (_Float16)p1.z, (_Float16)p1.w};
        accT[mt] = __builtin_amdgcn_mfma_f32_16x16x32_f16(at, bx[ks],
                                                          accT[mt], 0, 0, 0);
        accP[mt] = __builtin_amdgcn_mfma_f32_16x16x32_f16(ap, bx[ks],
                                                          accP[mt], 0, 0, 0);
      }

    // D -> per-wave slab: lane = col q_loc=l15, rows c2 = mt*16+quad*4+r
#pragma unroll
    for (int mt = 0; mt < 2; mt++) {
      h4 tv, pv;
#pragma unroll
      for (int r = 0; r < 4; r++) {
        tv[r] = (_Float16)(accT[mt][r] * SCALE2);
        pv[r] = (_Float16)accP[mt][r];
      }
      *reinterpret_cast<h4*>(&th_s[wv][l15][mt * 16 + quad * 4]) = tv;
      *reinterpret_cast<h4*>(&ph_s[wv][l15][mt * 16 + quad * 4]) = pv;
    }
    // same-wave ds write->read ordering suffices (slabs are wave-local)

    // theta B-frags out
    h8 tfrag = *reinterpret_cast<const h8*>(&th_s[wv][l15][quad * 8]);
    *reinterpret_cast<h8*>(
        thf + (((size_t)(bt * NKT + qt) * 4 + wv) * 64 + lane) * 8) = tfrag;

    // phi record chunk
    h8 pfrag = *reinterpret_cast<const h8*>(&ph_s[wv][l15][quad * 8]);
    *reinterpret_cast<h8*>(rb + wv * 512 + lane * 8) = pfrag;
  } else {
    // waves 4-7: key-permuted x chunks (g,ct): w2 = wv-4 owns g=w2>>1,
    // ct=(w2&1)*2+{0,1}. slot j<4 -> key 32g+quad*4+j ; j>=4 -> +16.
    const int w2 = wv - 4;
    const int g = w2 >> 1;
#pragma unroll
    for (int ct2 = 0; ct2 < 2; ct2++) {
      const int ct = (w2 & 1) * 2 + ct2;
      h8 v;
#pragma unroll
      for (int j = 0; j < 4; j++) {
        v[j] = (_Float16)x_s[32 * g + quad * 4 + j][ct * 16 + l15];
        v[4 + j] = (_Float16)x_s[32 * g + 16 + quad * 4 + j][ct * 16 + l15];
      }
      *reinterpret_cast<h8*>(rb + 2048 + (g * 4 + ct) * 512 + lane * 8) = v;
    }
  }
}

// ---------------------------------------------------------------------------
// k_attn: grid (8, 96) = 768 blocks = exactly 3/CU. 192 thr = 3 waves.
// RESTRUCTURED from kg-split to p-split: each wave owns ONE 16-col pf
// group of the block's 48p strip and streams ALL 36 records. The 3 waves
// read IDENTICAL addresses in lockstep -> L1 serves 2 of 3 waves, cutting
// the per-CU L2-line (MSHR) demand ~3x. (kg-split had every wave on
// distinct bytes: ~144 outstanding wave-loads/CU >> MSHR capacity ->
// fill-serialized at ~27 B/cy/CU = the measured 32.6 us.)
// Each wave owns complete softmax rows -> NO kg-combine: zero LDS, zero
// barriers, epilogue fully in-register. VGPR demand ~115; (192,3) caps at
// ~168 (no spill, guaranteed 3 waves/SIMD -- R8 lesson: cap above demand).
// ---------------------------------------------------------------------------
__global__ __launch_bounds__(192, 3) void k_attn(
    const float* __restrict__ x, const _Float16* __restrict__ thf,
    const _Float16* __restrict__ rec, const float* __restrict__ ow,
    float* __restrict__ out) {
  const int strip = blockIdx.y >> 1;  // [0,48), 48 p each
  const int bt = SWIZ_BT(blockIdx.x, blockIdx.y);
  const int b = bt >> 3, t = bt & 7;
  const int tid = threadIdx.x;
  const int pf = tid >> 6, lane = tid & 63;  // wave = pf group 0..2
  const int quad = lane >> 4, l15 = lane & 15;

  // theta B-frag for this wave's 16-col group
  const h8 bth = *reinterpret_cast<const h8*>(
      thf + (((size_t)bt * 144 + strip * 3 + pf) * 64 + lane) * 8);

  const _Float16* recb = rec + (size_t)bt * NKT * 6144 + lane * 8;

  const f4 zero = {0.f, 0.f, 0.f, 0.f};
  f4 O[4];  // [ct]: rows c=ct*16+quad*4+r, col p=strip*48+pf*16+l15
#pragma unroll
  for (int ct = 0; ct < 4; ct++) O[ct] = zero;
  float lsum = 0.f;

#pragma unroll 2
  for (int i = 0; i < NKT; i++) {
    const _Float16* _p = recb + (size_t)i * 6144;
    h8 buf[12];  // [0..3] phi A-frags, [4..11] x A-frags (g*4+ct)
#pragma unroll
    for (int j = 0; j < 12; j++)
      buf[j] = *reinterpret_cast<const h8*>(_p + j * 512);

    f4 s[4];
#pragma unroll
    for (int nt = 0; nt < 4; nt++)
      s[nt] =
          __builtin_amdgcn_mfma_f32_16x16x32_f16(buf[nt], bth, zero, 0, 0, 0);
#pragma unroll
    for (int g = 0; g < 2; g++) {
      h8 bw;
#pragma unroll
      for (int r = 0; r < 4; r++) {
        float w0 = EXP2(s[2 * g][r]);
        float w1 = EXP2(s[2 * g + 1][r]);
        lsum += w0 + w1;
        bw[r] = (_Float16)w0;
        bw[4 + r] = (_Float16)w1;
      }
#pragma unroll
      for (int ct = 0; ct < 4; ct++)
        O[ct] = __builtin_amdgcn_mfma_f32_16x16x32_f16(buf[4 + g * 4 + ct], bw,
                                                       O[ct], 0, 0, 0);
    }
  }

  // denominator: combine quad groups (p = pf*16+l15 fixed across quads)
  lsum += __shfl_xor(lsum, 16);
  lsum += __shfl_xor(lsum, 32);
  const float inv = 1.f / lsum;

  // f in B-frag layout for out-proj: B[k=c=ct*16+quad*4+r][n=p=l15]
  h4 bf[4];
#pragma unroll
  for (int ct = 0; ct < 4; ct++)
#pragma unroll
    for (int r = 0; r < 4; r++) bf[ct][r] = (_Float16)(O[ct][r] * inv);

  f4 D3[4] = {zero, zero, zero, zero};
#pragma unroll
  for (int mt = 0; mt < 4; mt++)
#pragma unroll
    for (int ct = 0; ct < 4; ct++) {
      const float* wrow = ow + (size_t)(mt * 16 + l15) * CC + ct * 16 + quad * 4;
      float4 u = *reinterpret_cast<const float4*>(wrow);
      h4 aw = {(_Float16)u.x, (_Float16)u.y, (_Float16)u.z, (_Float16)u.w};
      D3[mt] = __builtin_amdgcn_mfma_f32_16x16x16f16(aw, bf[ct], D3[mt], 0, 0, 0);
    }

  // stores with fp32 residual; wave pf owns p block strip*48 + pf*16
  const int p0 = strip * 48 + pf * 16 + l15;
#pragma unroll
  for (int mt = 0; mt < 4; mt++)
#pragma unroll
    for (int r = 0; r < 4; r++) {
      const int o = mt * 16 + quad * 4 + r;
      const size_t base = ((size_t)(b * CC + o) * TT + t) * PP + p0;
      out[base] = D3[mt][r] + x[base];
    }
}

extern "C" void kernel_launch(void* const* d_in, const int* in_sizes, int n_in,
                              void* d_out, int out_size, void* d_ws,
                              size_t ws_size, hipStream_t stream) {
  (void)in_sizes; (void)n_in; (void)out_size; (void)ws_size;
  const float* x = (const float*)d_in[0];
  const float* tw = (const float*)d_in[1];
  const float* pw = (const float*)d_in[2];
  const float* ow = (const float*)d_in[3];
  float* out = (float*)d_out;

  _Float16* thf = (_Float16*)d_ws;                      // 2.25 MB
  _Float16* rec = thf + (size_t)BT * NKT * 4 * 64 * 8;  // 7.08 MB

  k_prep<<<dim3(8, 72), 512, 0, stream>>>(x, tw, pw, thf, rec);
  k_attn<<<dim3(8, 96), 192, 0, stream>>>(x, thf, rec, ow, out);
}

// Round 11
// 94.347 us; speedup vs baseline: 1.2314x; 1.2314x over previous
//
#include <hip/hip_runtime.h>
#include <hip/hip_bf16.h>

// Problem constants (B,C,T,H,W = 2,64,8,48,48)
#define CC 64
#define TT 8
#define PP 2304        // 48*48
#define C2 32
#define BT 16          // B*T
#define NKT 36         // key tiles of 64
#define QKT 9          // records per key-group (4-way split)
// log2(e)/sqrt(32): folds softmax scale AND exp->exp2 into theta pre-scale
#define SCALE2 0.25503486f

using h8 = __attribute__((ext_vector_type(8))) _Float16;  // 4 VGPRs
using h4 = __attribute__((ext_vector_type(4))) _Float16;  // 2 VGPRs
using f4 = __attribute__((ext_vector_type(4))) float;     // MFMA C/D frag

#if __has_builtin(__builtin_amdgcn_exp2f)
#define EXP2(v) __builtin_amdgcn_exp2f(v)
#else
#define EXP2(v) exp2f(v)
#endif

// XCD swizzle: dispatch round-robins XCDs by linear block id; fixing
// blockIdx.x per bt puts all consumers of one bt on ONE XCD whose 4 MB L2
// holds that bt's ~870 KB record set. Perf heuristic only.
#define SWIZ_BT(xcd, g) ((xcd) + 8 * ((g) & 1))

// Workspace (_Float16):
//  thf[bt][g16 (144 of 16p)][lane][8]   theta B-frags (pre-scaled)  2.25 MB
//  rec[bt][kt] = 12 KB record:                                      7.08 MB
//     halves [0,2048):  phi A-frags   [nt(4)][lane][8]
//     halves [2048,6144): x PV A-frags [g(2)][ct(4)][lane][8], packed in the
//       K=32 key-permuted order: slot k=quad*8+j holds key
//       32g + (j<4 ? quad*4+j : 16+quad*4+(j-4)).  With this order the PV
//       B-operand is just the concat of two S D-frag h4's -> full-rate
//       16x16x32 PV MFMAs with zero cross-lane traffic.
// Every k_attn load is base + lane*16B: fully coalesced dwordx4.

// ---------------------------------------------------------------------------
// k_prep: grid (8, 144) = 1152 blocks (4.5/CU, +11% tail vs 576's +33%).
// Each block owns ONE g-half (32 q's) of a (bt,qt) unit. 256 thr = 4 waves:
// waves 0-1 project theta/phi for their 16-q slab (thf group g*2+wv, phi
// chunk nt=g*2+wv); waves 2-3 pack the g's four key-permuted x chunks.
// ---------------------------------------------------------------------------
__global__ __launch_bounds__(256) void k_prep(
    const float* __restrict__ x, const float* __restrict__ tw,
    const float* __restrict__ pw, _Float16* __restrict__ thf,
    _Float16* __restrict__ rec) {
  const int bt = SWIZ_BT(blockIdx.x, blockIdx.y);
  const int qt = blockIdx.y >> 2;        // 0..35
  const int g = (blockIdx.y >> 1) & 1;   // 0..1
  const int b = bt >> 3, t = bt & 7;
  const int tid = threadIdx.x;
  const int wv = tid >> 6, lane = tid & 63;
  const int quad = lane >> 4, l15 = lane & 15;

  __shared__ __align__(16) float x_s[32][68];         // [q_loc][c]
  __shared__ __align__(16) _Float16 th_s[2][16][32];  // waves 0-1 slabs
  __shared__ __align__(16) _Float16 ph_s[2][16][32];

  const size_t xslice = ((size_t)b * CC * TT + t) * PP;
  const int qg0 = qt * 64 + g * 32;  // this block's 32 q's
  _Float16* rb = rec + (size_t)(bt * NKT + qt) * 6144;
  const f4 zero = {0.f, 0.f, 0.f, 0.f};

  // stage x patch (64c x 32q) transposed to [q][c]; float4 along q
  {
    const int qoff = (tid & 7) * 4;
    const int c0 = tid >> 3;  // 0..31
#pragma unroll
    for (int ppass = 0; ppass < 2; ppass++) {
      const int c = ppass * 32 + c0;
      float4 u = *reinterpret_cast<const float4*>(
          &x[xslice + (size_t)c * (TT * PP) + qg0 + qoff]);
      x_s[qoff + 0][c] = u.x;
      x_s[qoff + 1][c] = u.y;
      x_s[qoff + 2][c] = u.z;
      x_s[qoff + 3][c] = u.w;
    }
  }
  __syncthreads();

  if (wv < 2) {
    // projections for q-slab wv: D[m=c2][n=q16] = W[c2][c].x[q][c], K=64
    h8 bx[2];
#pragma unroll
    for (int ks = 0; ks < 2; ks++) {
      const float* row = &x_s[wv * 16 + l15][ks * 32 + quad * 8];
      float4 u0 = *reinterpret_cast<const float4*>(row);
      float4 u1 = *reinterpret_cast<const float4*>(row + 4);
      bx[ks][0] = (_Float16)u0.x; bx[ks][1] = (_Float16)u0.y;
      bx[ks][2] = (_Float16)u0.z; bx[ks][3] = (_Float16)u0.w;
      bx[ks][4] = (_Float16)u1.x; bx[ks][5] = (_Float16)u1.y;
      bx[ks][6] = (_Float16)u1.z; bx[ks][7] = (_Float16)u1.w;
    }

    const float* twt = tw + t * C2 * CC;
    const float* pwt = pw + t * C2 * CC;
    f4 accT[2] = {zero, zero}, accP[2] = {zero, zero};
#pragma unroll
    for (int mt = 0; mt < 2; mt++)
#pragma unroll
      for (int ks = 0; ks < 2; ks++) {
        const float* wr = twt + (mt * 16 + l15) * CC + ks * 32 + quad * 8;
        const float* pr = pwt + (mt * 16 + l15) * CC + ks * 32 + quad * 8;
        float4 a0 = *reinterpret_cast<const float4*>(wr);
        float4 a1 = *reinterpret_cast<const float4*>(wr + 4);
        float4 p0 = *reinterpret_cast<const float4*>(pr);
        float4 p1 = *reinterpret_cast<const float4*>(pr + 4);
        h8 at = {(_Float16)a0.x, (_Float16)a0.y, (_Float16)a0.z,
                 (_Float16)a0.w, (_Float16)a1.x, (_Float16)a1.y,
                 (_Float16)a1.z, (_Float16)a1.w};
        h8 ap = {(_Float16)p0.x, (_Float16)p0.y, (_Float16)p0.z,
                 (_Float16)p0.w, (_Float16)p1.x, (_Float16)p1.y,
                 (_Float16)p1.z, (_Float16)p1.w};
        accT[mt] = __builtin_amdgcn_mfma_f32_16x16x32_f16(at, bx[ks],
                                                          accT[mt], 0, 0, 0);
        accP[mt] = __builtin_amdgcn_mfma_f32_16x16x32_f16(ap, bx[ks],
                                                          accP[mt], 0, 0, 0);
      }

    // D -> per-wave slab: lane = col q=l15, rows c2 = mt*16+quad*4+r
#pragma unroll
    for (int mt = 0; mt < 2; mt++) {
      h4 tv, pv;
#pragma unroll
      for (int r = 0; r < 4; r++) {
        tv[r] = (_Float16)(accT[mt][r] * SCALE2);
        pv[r] = (_Float16)accP[mt][r];
      }
      *reinterpret_cast<h4*>(&th_s[wv][l15][mt * 16 + quad * 4]) = tv;
      *reinterpret_cast<h4*>(&ph_s[wv][l15][mt * 16 + quad * 4]) = pv;
    }
    // same-wave ds write->read ordering suffices (slabs are wave-local)

    // theta B-frag out: global 16-q group = qt*4 + g*2 + wv
    h8 tfrag = *reinterpret_cast<const h8*>(&th_s[wv][l15][quad * 8]);
    *reinterpret_cast<h8*>(
        thf + (((size_t)(bt * 144 + qt * 4 + g * 2 + wv)) * 64 + lane) * 8) =
        tfrag;

    // phi record chunk nt = g*2 + wv
    h8 pfrag = *reinterpret_cast<const h8*>(&ph_s[wv][l15][quad * 8]);
    *reinterpret_cast<h8*>(rb + (g * 2 + wv) * 512 + lane * 8) = pfrag;
  } else {
    // waves 2-3: key-permuted x chunks for this g. w2 = wv-2 owns
    // ct = w2*2 + {0,1}. slot j<4 -> local key quad*4+j ; j>=4 -> +16.
    const int w2 = wv - 2;
#pragma unroll
    for (int ct2 = 0; ct2 < 2; ct2++) {
      const int ct = w2 * 2 + ct2;
      h8 v;
#pragma unroll
      for (int j = 0; j < 4; j++) {
        v[j] = (_Float16)x_s[quad * 4 + j][ct * 16 + l15];
        v[4 + j] = (_Float16)x_s[16 + quad * 4 + j][ct * 16 + l15];
      }
      *reinterpret_cast<h8*>(rb + 2048 + (g * 4 + ct) * 512 + lane * 8) = v;
    }
  }
}

// ---------------------------------------------------------------------------
// k_attn: grid (8, 96) = 768 blocks = exactly 3/CU. 256 thr = 4 waves =
// 1 p-strip(48) x 4 key-groups (R9 structure). NEW: half-record software
// pipeline -- the record splits cleanly at g (S subtile nt needs only
// phi[nt]; PV g needs only x[g*4+ct]), so each half is 6 loads. Two named
// 24-VGPR buffers alternate; the next half's loads issue BEFORE the
// current half's compute, giving explicit prefetch distance the compiler
// cannot collapse to just-in-time (R10's VGPR=44 failure mode). VGPR
// ~140 < (256,3) cap ~170: no spill, occupancy unchanged.
// ---------------------------------------------------------------------------
__global__ __launch_bounds__(256, 3) void k_attn(
    const float* __restrict__ x, const _Float16* __restrict__ thf,
    const _Float16* __restrict__ rec, const float* __restrict__ ow,
    float* __restrict__ out) {
  const int strip = blockIdx.y >> 1;  // [0,48), 48 p each
  const int bt = SWIZ_BT(blockIdx.x, blockIdx.y);
  const int b = bt >> 3, t = bt & 7;
  const int tid = threadIdx.x;
  const int kg = tid >> 6, lane = tid & 63;
  const int quad = lane >> 4, l15 = lane & 15;

  __shared__ __align__(16) float exch[4 * 3 * 16 * 64];  // 48 KB
  __shared__ float exl[4 * 3 * 64];                      // 3 KB

  // theta B-frags for this strip's three 16-col groups
  h8 bth[3];
#pragma unroll
  for (int pf = 0; pf < 3; pf++)
    bth[pf] = *reinterpret_cast<const h8*>(
        thf + (((size_t)bt * 144 + strip * 3 + pf) * 64 + lane) * 8);

  const _Float16* recb =
      rec + ((size_t)bt * NKT + (size_t)kg * QKT) * 6144 + lane * 8;

  const f4 zero = {0.f, 0.f, 0.f, 0.f};
  f4 O[4][3];  // [ct][pf]: rows c=ct*16+quad*4+r, col p=strip*48+pf*16+l15
#pragma unroll
  for (int ct = 0; ct < 4; ct++)
#pragma unroll
    for (int pf = 0; pf < 3; pf++) O[ct][pf] = zero;
  float lsum[3] = {0.f, 0.f, 0.f};

  // half-record buffers: [0]=phi(2g), [1]=phi(2g+1), [2..5]=x(g,ct)
  h8 hA[6], hB[6];

#define LOADH(BUF, i, gg)                                                    \
  {                                                                          \
    const _Float16* _p = recb + (size_t)(i)*6144;                            \
    BUF[0] = *reinterpret_cast<const h8*>(_p + (2 * (gg)) * 512);            \
    BUF[1] = *reinterpret_cast<const h8*>(_p + (2 * (gg) + 1) * 512);        \
    _Pragma("unroll") for (int c = 0; c < 4; c++)                            \
        BUF[2 + c] =                                                         \
        *reinterpret_cast<const h8*>(_p + 2048 + ((gg)*4 + c) * 512);        \
  }

#define COMPH(BUF)                                                          \
  {                                                                         \
    _Pragma("unroll") for (int pf = 0; pf < 3; pf++) {                      \
      f4 sA = __builtin_amdgcn_mfma_f32_16x16x32_f16(BUF[0], bth[pf], zero, \
                                                     0, 0, 0);              \
      f4 sB = __builtin_amdgcn_mfma_f32_16x16x32_f16(BUF[1], bth[pf], zero, \
                                                     0, 0, 0);              \
      h8 bw;                                                                \
      _Pragma("unroll") for (int r = 0; r < 4; r++) {                       \
        float w0 = EXP2(sA[r]);                                             \
        float w1 = EXP2(sB[r]);                                             \
        lsum[pf] += w0 + w1;                                                \
        bw[r] = (_Float16)w0;                                               \
        bw[4 + r] = (_Float16)w1;                                           \
      }                                                                     \
      _Pragma("unroll") for (int ct = 0; ct < 4; ct++)                      \
          O[ct][pf] = __builtin_amdgcn_mfma_f32_16x16x32_f16(               \
              BUF[2 + ct], bw, O[ct][pf], 0, 0, 0);                         \
    }                                                                       \
  }

  // 18 halves (9 records x 2 g), one-half prefetch distance, fully unrolled
  LOADH(hA, 0, 0);
#pragma unroll
  for (int h = 0; h < 18; h++) {
    const int hn = h + 1;
    if ((h & 1) == 0) {
      if (hn < 18) LOADH(hB, hn >> 1, hn & 1);
      COMPH(hA);
    } else {
      if (hn < 18) LOADH(hA, hn >> 1, hn & 1);
      COMPH(hB);
    }
  }
#undef LOADH
#undef COMPH

  // partial denominators: combine quad groups (p = pf*16+l15 fixed)
#pragma unroll
  for (int pf = 0; pf < 3; pf++) {
    lsum[pf] += __shfl_xor(lsum[pf], 16);
    lsum[pf] += __shfl_xor(lsum[pf], 32);
  }

  // all-to-all kg combine: publish everything; waves 0..2 finish pf=kg
#pragma unroll
  for (int pf = 0; pf < 3; pf++) {
#pragma unroll
    for (int ct = 0; ct < 4; ct++)
#pragma unroll
      for (int r = 0; r < 4; r++)
        exch[((kg * 3 + pf) * 16 + ct * 4 + r) * 64 + lane] = O[ct][pf][r];
    exl[(kg * 3 + pf) * 64 + lane] = lsum[pf];
  }
  __syncthreads();

  if (kg < 3) {
    float ls = 0.f;
#pragma unroll
    for (int src = 0; src < 4; src++) ls += exl[(src * 3 + kg) * 64 + lane];
    const float inv = 1.f / ls;

    // f in B-frag layout for out-proj: B[k=c=ct*16+quad*4+r][n=p=l15]
    h4 bf[4];
#pragma unroll
    for (int ct = 0; ct < 4; ct++)
#pragma unroll
      for (int r = 0; r < 4; r++) {
        float acc = 0.f;
#pragma unroll
        for (int src = 0; src < 4; src++)
          acc += exch[((src * 3 + kg) * 16 + ct * 4 + r) * 64 + lane];
        bf[ct][r] = (_Float16)(acc * inv);
      }

    f4 D3[4] = {zero, zero, zero, zero};
#pragma unroll
    for (int mt = 0; mt < 4; mt++)
#pragma unroll
      for (int ct = 0; ct < 4; ct++) {
        const float* wrow =
            ow + (size_t)(mt * 16 + l15) * CC + ct * 16 + quad * 4;
        float4 u = *reinterpret_cast<const float4*>(wrow);
        h4 aw = {(_Float16)u.x, (_Float16)u.y, (_Float16)u.z, (_Float16)u.w};
        D3[mt] =
            __builtin_amdgcn_mfma_f32_16x16x16f16(aw, bf[ct], D3[mt], 0, 0, 0);
      }

    // stores with fp32 residual; wave kg owns p block strip*48 + kg*16
    const int p0 = strip * 48 + kg * 16 + l15;
#pragma unroll
    for (int mt = 0; mt < 4; mt++)
#pragma unroll
      for (int r = 0; r < 4; r++) {
        const int o = mt * 16 + quad * 4 + r;
        const size_t base = ((size_t)(b * CC + o) * TT + t) * PP + p0;
        out[base] = D3[mt][r] + x[base];
      }
  }
}

extern "C" void kernel_launch(void* const* d_in, const int* in_sizes, int n_in,
                              void* d_out, int out_size, void* d_ws,
                              size_t ws_size, hipStream_t stream) {
  (void)in_sizes; (void)n_in; (void)out_size; (void)ws_size;
  const float* x = (const float*)d_in[0];
  const float* tw = (const float*)d_in[1];
  const float* pw = (const float*)d_in[2];
  const float* ow = (const float*)d_in[3];
  float* out = (float*)d_out;

  _Float16* thf = (_Float16*)d_ws;                      // 2.25 MB
  _Float16* rec = thf + (size_t)BT * NKT * 4 * 64 * 8;  // 7.08 MB

  k_prep<<<dim3(8, 144), 256, 0, stream>>>(x, tw, pw, thf, rec);
  k_attn<<<dim3(8, 96), 256, 0, stream>>>(x, thf, rec, ow, out);
}